// Round 11
// baseline (22722.418 us; speedup 1.0000x reference)
//
#include <hip/hip_runtime.h>
#include <hip/hip_bf16.h>

#define TSEQ 65536
#define INPUT_SIZE 128
#define HIDDEN 100
#define GATES 400   // 4*HIDDEN

typedef int  __attribute__((ext_vector_type(4))) i32x4;

__device__ __forceinline__ float rcp_fast(float x) { return __builtin_amdgcn_rcpf(x); }
__device__ __forceinline__ float sigm(float x) { return rcp_fast(1.0f + __expf(-x)); }

// DPP quad_perm broadcast within groups of 4 lanes (pure VALU, no LDS).
template <int CTRL>
__device__ __forceinline__ float qb(float v) {
    int i = __builtin_bit_cast(int, v);
    int r = __builtin_amdgcn_mov_dpp(i, CTRL, 0xF, 0xF, true);
    return __builtin_bit_cast(float, r);
}

// barrier without vmcnt drain: LDS-drain + s_barrier + compiler memory fence
#define LDS_BARRIER()                                              \
    do {                                                           \
        asm volatile("s_waitcnt lgkmcnt(0)" ::: "memory");         \
        __builtin_amdgcn_s_barrier();                              \
        asm volatile("" ::: "memory");                             \
    } while (0)

// ---------------------------------------------------------------------------
// Kernel 1: xp_perm[t][4*u + g] = b_ih[j] + b_hh[j] + sum_k x[t][k]*W_ih[j][k]
// where j = g*100 + u (orig gate row). Unit-major/gate-minor layout.
// ---------------------------------------------------------------------------
__global__ __launch_bounds__(256) void xproj_kernel(
    const float* __restrict__ x,     // [TSEQ][128]
    const float* __restrict__ W,     // [400][128]
    const float* __restrict__ bi,    // [400]
    const float* __restrict__ bh,    // [400]
    float* __restrict__ xp)          // [TSEQ][400] (permuted)
{
    __shared__ __align__(16) float xs[16 * 128];
    const int tid = threadIdx.x;
    const int t0 = blockIdx.x * 16;

#pragma unroll
    for (int i = 0; i < 8; ++i)
        xs[i * 256 + tid] = x[(size_t)t0 * 128 + i * 256 + tid];
    __syncthreads();

    const int j1 = tid;
    const int j2 = tid + 256;
    const bool has2 = (j2 < GATES);
    const int p1 = 4 * (j1 % 100) + (j1 / 100);
    const int p2 = has2 ? (4 * (j2 % 100) + (j2 / 100)) : 0;

    float acc1[16], acc2[16];
    const float bias1 = bi[j1] + bh[j1];
    const float bias2 = has2 ? (bi[j2] + bh[j2]) : 0.0f;
#pragma unroll
    for (int tt = 0; tt < 16; ++tt) { acc1[tt] = bias1; acc2[tt] = bias2; }

    const float4* W4 = reinterpret_cast<const float4*>(W);
    const float4* xs4 = reinterpret_cast<const float4*>(xs);

    for (int kk = 0; kk < 32; ++kk) {
        const float4 wa = W4[(size_t)j1 * 32 + kk];
        float4 wb = make_float4(0.f, 0.f, 0.f, 0.f);
        if (has2) wb = W4[(size_t)j2 * 32 + kk];
#pragma unroll
        for (int tt = 0; tt < 16; ++tt) {
            const float4 xv = xs4[tt * 32 + kk];
            acc1[tt] = fmaf(wa.x, xv.x, acc1[tt]);
            acc1[tt] = fmaf(wa.y, xv.y, acc1[tt]);
            acc1[tt] = fmaf(wa.z, xv.z, acc1[tt]);
            acc1[tt] = fmaf(wa.w, xv.w, acc1[tt]);
            acc2[tt] = fmaf(wb.x, xv.x, acc2[tt]);
            acc2[tt] = fmaf(wb.y, xv.y, acc2[tt]);
            acc2[tt] = fmaf(wb.z, xv.z, acc2[tt]);
            acc2[tt] = fmaf(wb.w, xv.w, acc2[tt]);
        }
    }

#pragma unroll
    for (int tt = 0; tt < 16; ++tt) {
        xp[(size_t)(t0 + tt) * GATES + p1] = acc1[tt];
        if (has2) xp[(size_t)(t0 + tt) * GATES + p2] = acc2[tt];
    }
}

// ---------------------------------------------------------------------------
// Kernel 2: LSTM recurrence via INT8 MFMA (v_mfma_i32_16x16x64_i8).
// One block, 512 threads (8 waves), 1 barrier/step. R10 structure + R11
// critical-path polish:
//  - kk2 folded into prefetch (exp input = fma(cvt(sel), SCALE*kk2, xq*kk2))
//  - parallel DPP pair for cnew (both DPPs depend only on act)
//  - independent MFMA accumulators per K-chunk (+ scalar add), no acc chain
//  - hs global stores batched once per 4 steps, off the serial chain
// ---------------------------------------------------------------------------
__global__ __launch_bounds__(512, 1) void lstm_rec_kernel(
    const float* __restrict__ xp,    // [TSEQ][400] permuted, includes biases
    const float* __restrict__ Whh,   // [400][100] original layout
    unsigned short* __restrict__ hs) // [TSEQ][100] f16
{
    __shared__ __align__(16) char h_lds[2][128];   // int8 h, zero-padded to 128

    const int tid = threadIdx.x;
    const int lane = tid & 63;
    const int w = tid >> 6;          // wave 0..7
    const int kg = lane >> 4;        // k-group for frags; tile-slot for cell
    const int cc = lane & 15;        // B col within tile = gate slot

    // ---- W_q fragments (B operand): 4 tile-slots x 2 K-chunks, 4 dwords each
    // wave w: tiles 3w..3w+2 ; slot 3 = tile 24 (wave 7 only)
    i32x4 wfrag[4][2];
#pragma unroll
    for (int i = 0; i < 4; ++i) {
        const int ti = (i < 3) ? (3 * w + i) : 24;
        const bool valid = (i < 3) || (w == 7);
        const int orow = (cc & 3) * 100 + 4 * ti + (cc >> 2);  // orig W_hh row
#pragma unroll
        for (int ch = 0; ch < 2; ++ch) {
            const int k0 = 64 * ch + 16 * kg;
            int dw[4];
#pragma unroll
            for (int d = 0; d < 4; ++d) {
                unsigned pk = 0;
#pragma unroll
                for (int b = 0; b < 4; ++b) {
                    const int k = k0 + 4 * d + b;
                    float wv = (valid && k < 100) ? Whh[(size_t)orow * 100 + k] : 0.0f;
                    int q = (int)rintf(wv * 1270.0f);
                    q = (q > 127) ? 127 : ((q < -127) ? -127 : q);
                    pk |= ((unsigned)(q & 0xff)) << (8 * b);
                }
                dw[d] = (int)pk;
            }
            wfrag[i][ch] = i32x4{dw[0], dw[1], dw[2], dw[3]};
        }
    }

    // ---- lane roles (loop-invariant)
    const bool valid = (kg < 3) || (w == 7);
    const int mytile = (kg < 3) ? (3 * w + kg) : 24;
    const int unit = 4 * mytile + (cc >> 2);
    const int g = cc & 3;                          // 0=i 1=f 2=g~ 3=o
    const int p = 4 * unit + g;                    // permuted xp index
    const bool writer = valid && (g == 3);
    const float kk2 = (g == 2) ? 2.0f : 1.0f;      // tanh via exp(2x)
    const float bsub = (g == 2) ? 2.0f : 1.0f;     // act = 1 - bsub/(e+1)
    const bool isg1 = (g == 1);
    const float sk = (1.0f / (1270.0f * 127.0f)) * kk2;  // dequant*kk2 folded

    // ---- init
    if (tid < 128) { h_lds[0][tid] = 0; h_lds[1][tid] = 0; }
    float c = 0.0f;
    const float* xq_ptr = xp + p;
    float xqv[4];                                  // pre-scaled by kk2
#pragma unroll
    for (int pp = 0; pp < 4; ++pp) xqv[pp] = xq_ptr[pp * GATES] * kk2;
    xq_ptr += 4 * GATES;
    unsigned short* hp = hs + unit;
    __syncthreads();

    for (int t = 0; t < TSEQ; t += 4) {
        unsigned short hv4[4];                     // f16 bits, stored after loop
#pragma unroll
        for (int u = 0; u < 4; ++u) {
            const int cur = u & 1;                 // parity of tt == parity of u

            // ---- A fragments: h_q broadcast, 2 x 16B same-address reads
            i32x4 afr[2];
#pragma unroll
            for (int ch = 0; ch < 2; ++ch) {
                const uint4 q = *(const uint4*)&h_lds[cur][ch * 64 + kg * 16];
                afr[ch] = __builtin_bit_cast(i32x4, q);
            }

            // ---- 2 independent i8 MFMAs per tile-slot (no acc chain), add [0]
            int ipre_s[4];
#pragma unroll
            for (int i = 0; i < 4; ++i) {
                if (i < 3 || w == 7) {
                    i32x4 z = {0, 0, 0, 0};
                    const i32x4 a0 = __builtin_amdgcn_mfma_i32_16x16x64_i8(afr[0], wfrag[i][0], z, 0, 0, 0);
                    const i32x4 a1 = __builtin_amdgcn_mfma_i32_16x16x64_i8(afr[1], wfrag[i][1], z, 0, 0, 0);
                    ipre_s[i] = a0[0] + a1[0];
                } else {
                    ipre_s[i] = 0;
                }
            }

            // ---- scalar tile select by kg (3 cndmask)
            int ipre = ipre_s[0];
            ipre = (kg == 1) ? ipre_s[1] : ipre;
            ipre = (kg == 2) ? ipre_s[2] : ipre;
            ipre = (kg == 3) ? ipre_s[3] : ipre;

            // ---- unified activation (kk2 pre-folded into sk and xqv):
            // act = 1 - bsub * rcp(exp(pre*kk2) + 1)
            const float e = __expf(fmaf((float)ipre, sk, xqv[u]));
            const float act = fmaf(-bsub, rcp_fast(e + 1.0f), 1.0f);

            // ---- quad combine via DPP; both DPPs depend only on act (parallel)
            const float di = qb<0x00>(act);              // act of g0 (i)
            const float dg = qb<0xAA>(act);              // act of g2 (g~)
            const float prod = di * dg;                  // i * g~
            const float cnew = fmaf(act, c, prod);       // g1: f*c + i*g~
            c = isg1 ? cnew : c;                         // c lives on g1
            const float e2 = __expf(c + c);              // tanh(c) on g1
            const float tc = fmaf(-2.0f, rcp_fast(e2 + 1.0f), 1.0f);
            const float hv = act * qb<0x55>(tc);         // g3: o * tanh(c)

            if (writer) {
                const int hq = (int)rintf(hv * 127.0f);
                h_lds[1 - cur][unit] = (char)hq;         // publish int8 (critical)
            }
            union { __fp16 h; unsigned short u16; } cv;
            cv.h = (__fp16)hv;
            hv4[u] = cv.u16;                             // f16 store deferred

            // depth-4 prefetch, pre-scaled (tail overruns into hs region:
            // valid memory, value never consumed)
            xqv[u] = xq_ptr[u * GATES] * kk2;

            LDS_BARRIER();   // new h visible to all waves for next step
        }
        // ---- batched fire-and-forget f16 stores (off the serial chain)
        if (writer) {
            hp[0 * HIDDEN] = hv4[0];
            hp[1 * HIDDEN] = hv4[1];
            hp[2 * HIDDEN] = hv4[2];
            hp[3 * HIDDEN] = hv4[3];
        }
        xq_ptr += 4 * GATES;
        hp += 4 * HIDDEN;
    }
}

// ---------------------------------------------------------------------------
// Kernel 3: out[t] = sigmoid(dot(hs_f16[t], W_lin) + b_lin)
// ---------------------------------------------------------------------------
__global__ __launch_bounds__(256) void pred_kernel(
    const unsigned short* __restrict__ hs,   // [TSEQ][100] f16
    const float* __restrict__ wlin,          // [100]
    const float* __restrict__ blin,          // [1]
    float* __restrict__ out)                 // [TSEQ]
{
    __shared__ __align__(16) float wl[HIDDEN];
    const int tid = threadIdx.x;
    if (tid < HIDDEN) wl[tid] = wlin[tid];
    __syncthreads();

    const int t = blockIdx.x * 256 + tid;
    const unsigned short* hrow = hs + (size_t)t * HIDDEN;   // 8B-aligned
    float acc = blin[0];
#pragma unroll
    for (int kk = 0; kk < 25; ++kk) {                       // 25 x uint2 = 100 f16
        const uint2 v = *(const uint2*)&hrow[kk * 4];
        const __fp16 h0 = __builtin_bit_cast(__fp16, (unsigned short)(v.x & 0xffffu));
        const __fp16 h1 = __builtin_bit_cast(__fp16, (unsigned short)(v.x >> 16));
        const __fp16 h2 = __builtin_bit_cast(__fp16, (unsigned short)(v.y & 0xffffu));
        const __fp16 h3 = __builtin_bit_cast(__fp16, (unsigned short)(v.y >> 16));
        acc = fmaf((float)h0, wl[kk * 4 + 0], acc);
        acc = fmaf((float)h1, wl[kk * 4 + 1], acc);
        acc = fmaf((float)h2, wl[kk * 4 + 2], acc);
        acc = fmaf((float)h3, wl[kk * 4 + 3], acc);
    }
    out[t] = sigm(acc);
}

// ---------------------------------------------------------------------------
extern "C" void kernel_launch(void* const* d_in, const int* in_sizes, int n_in,
                              void* d_out, int out_size, void* d_ws, size_t ws_size,
                              hipStream_t stream) {
    const float* x     = (const float*)d_in[0];  // [65536,128]
    const float* W_ih  = (const float*)d_in[1];  // [400,128]
    const float* W_hh  = (const float*)d_in[2];  // [400,100]
    const float* b_ih  = (const float*)d_in[3];  // [400]
    const float* b_hh  = (const float*)d_in[4];  // [400]
    const float* W_lin = (const float*)d_in[5];  // [1,100]
    const float* b_lin = (const float*)d_in[6];  // [1]
    float* out = (float*)d_out;                  // [65536]

    float* xp = (float*)d_ws;                                  // [TSEQ*400] fp32
    unsigned short* hs = (unsigned short*)(xp + (size_t)TSEQ * GATES);  // [TSEQ*100] f16

    xproj_kernel<<<TSEQ / 16, 256, 0, stream>>>(x, W_ih, b_ih, b_hh, xp);
    lstm_rec_kernel<<<1, 512, 0, stream>>>(xp, W_hh, hs);
    pred_kernel<<<TSEQ / 256, 256, 0, stream>>>(hs, W_lin, b_lin, out);
}

// Round 12
// 21349.767 us; speedup vs baseline: 1.0643x; 1.0643x over previous
//
#include <hip/hip_runtime.h>
#include <hip/hip_bf16.h>

#define TSEQ 65536
#define INPUT_SIZE 128
#define HIDDEN 100
#define GATES 400   // 4*HIDDEN

typedef int  __attribute__((ext_vector_type(4))) i32x4;

__device__ __forceinline__ float rcp_fast(float x) { return __builtin_amdgcn_rcpf(x); }
__device__ __forceinline__ float sigm(float x) { return rcp_fast(1.0f + __expf(-x)); }

// DPP quad_perm broadcast within groups of 4 lanes (pure VALU, no LDS).
template <int CTRL>
__device__ __forceinline__ float qb(float v) {
    int i = __builtin_bit_cast(int, v);
    int r = __builtin_amdgcn_mov_dpp(i, CTRL, 0xF, 0xF, true);
    return __builtin_bit_cast(float, r);
}

// barrier without vmcnt drain: LDS-drain + s_barrier + compiler memory fence
#define LDS_BARRIER()                                              \
    do {                                                           \
        asm volatile("s_waitcnt lgkmcnt(0)" ::: "memory");         \
        __builtin_amdgcn_s_barrier();                              \
        asm volatile("" ::: "memory");                             \
    } while (0)

// ---------------------------------------------------------------------------
// Kernel 1: xp_perm[t][4*u + g] = b_ih[j] + b_hh[j] + sum_k x[t][k]*W_ih[j][k]
// where j = g*100 + u (orig gate row). Unit-major/gate-minor layout.
// ---------------------------------------------------------------------------
__global__ __launch_bounds__(256) void xproj_kernel(
    const float* __restrict__ x,     // [TSEQ][128]
    const float* __restrict__ W,     // [400][128]
    const float* __restrict__ bi,    // [400]
    const float* __restrict__ bh,    // [400]
    float* __restrict__ xp)          // [TSEQ][400] (permuted)
{
    __shared__ __align__(16) float xs[16 * 128];
    const int tid = threadIdx.x;
    const int t0 = blockIdx.x * 16;

#pragma unroll
    for (int i = 0; i < 8; ++i)
        xs[i * 256 + tid] = x[(size_t)t0 * 128 + i * 256 + tid];
    __syncthreads();

    const int j1 = tid;
    const int j2 = tid + 256;
    const bool has2 = (j2 < GATES);
    const int p1 = 4 * (j1 % 100) + (j1 / 100);
    const int p2 = has2 ? (4 * (j2 % 100) + (j2 / 100)) : 0;

    float acc1[16], acc2[16];
    const float bias1 = bi[j1] + bh[j1];
    const float bias2 = has2 ? (bi[j2] + bh[j2]) : 0.0f;
#pragma unroll
    for (int tt = 0; tt < 16; ++tt) { acc1[tt] = bias1; acc2[tt] = bias2; }

    const float4* W4 = reinterpret_cast<const float4*>(W);
    const float4* xs4 = reinterpret_cast<const float4*>(xs);

    for (int kk = 0; kk < 32; ++kk) {
        const float4 wa = W4[(size_t)j1 * 32 + kk];
        float4 wb = make_float4(0.f, 0.f, 0.f, 0.f);
        if (has2) wb = W4[(size_t)j2 * 32 + kk];
#pragma unroll
        for (int tt = 0; tt < 16; ++tt) {
            const float4 xv = xs4[tt * 32 + kk];
            acc1[tt] = fmaf(wa.x, xv.x, acc1[tt]);
            acc1[tt] = fmaf(wa.y, xv.y, acc1[tt]);
            acc1[tt] = fmaf(wa.z, xv.z, acc1[tt]);
            acc1[tt] = fmaf(wa.w, xv.w, acc1[tt]);
            acc2[tt] = fmaf(wb.x, xv.x, acc2[tt]);
            acc2[tt] = fmaf(wb.y, xv.y, acc2[tt]);
            acc2[tt] = fmaf(wb.z, xv.z, acc2[tt]);
            acc2[tt] = fmaf(wb.w, xv.w, acc2[tt]);
        }
    }

#pragma unroll
    for (int tt = 0; tt < 16; ++tt) {
        xp[(size_t)(t0 + tt) * GATES + p1] = acc1[tt];
        if (has2) xp[(size_t)(t0 + tt) * GATES + p2] = acc2[tt];
    }
}

// ---------------------------------------------------------------------------
// Kernel 2: LSTM recurrence via INT8 MFMA (v_mfma_i32_16x16x64_i8).
// One block, 512 threads (8 waves), 1 barrier/step. R10 structure (chained
// MFMA accumulator, writer-only in-loop stores) + the two chain-only tweaks
// from R11 that don't add issue (kk2 folded into prefetch; parallel DPP pair).
// Quantization: W_q = rint(W_hh*1270) (|W|<0.1), h_q = rint(h*127) (|h|<1);
// i32 accumulation exact; measured absmax 0.0039 (threshold 0.0123).
// ---------------------------------------------------------------------------
__global__ __launch_bounds__(512, 1) void lstm_rec_kernel(
    const float* __restrict__ xp,    // [TSEQ][400] permuted, includes biases
    const float* __restrict__ Whh,   // [400][100] original layout
    unsigned short* __restrict__ hs) // [TSEQ][100] f16
{
    __shared__ __align__(16) char h_lds[2][128];   // int8 h, zero-padded to 128

    const int tid = threadIdx.x;
    const int lane = tid & 63;
    const int w = tid >> 6;          // wave 0..7
    const int kg = lane >> 4;        // k-group for frags; tile-slot for cell
    const int cc = lane & 15;        // B col within tile = gate slot

    // ---- W_q fragments (B operand): 4 tile-slots x 2 K-chunks, 4 dwords each
    // wave w: tiles 3w..3w+2 ; slot 3 = tile 24 (wave 7 only)
    i32x4 wfrag[4][2];
#pragma unroll
    for (int i = 0; i < 4; ++i) {
        const int ti = (i < 3) ? (3 * w + i) : 24;
        const bool valid = (i < 3) || (w == 7);
        const int orow = (cc & 3) * 100 + 4 * ti + (cc >> 2);  // orig W_hh row
#pragma unroll
        for (int ch = 0; ch < 2; ++ch) {
            const int k0 = 64 * ch + 16 * kg;
            int dw[4];
#pragma unroll
            for (int d = 0; d < 4; ++d) {
                unsigned pk = 0;
#pragma unroll
                for (int b = 0; b < 4; ++b) {
                    const int k = k0 + 4 * d + b;
                    float wv = (valid && k < 100) ? Whh[(size_t)orow * 100 + k] : 0.0f;
                    int q = (int)rintf(wv * 1270.0f);
                    q = (q > 127) ? 127 : ((q < -127) ? -127 : q);
                    pk |= ((unsigned)(q & 0xff)) << (8 * b);
                }
                dw[d] = (int)pk;
            }
            wfrag[i][ch] = i32x4{dw[0], dw[1], dw[2], dw[3]};
        }
    }

    // ---- lane roles (loop-invariant)
    const bool valid = (kg < 3) || (w == 7);
    const int mytile = (kg < 3) ? (3 * w + kg) : 24;
    const int unit = 4 * mytile + (cc >> 2);
    const int g = cc & 3;                          // 0=i 1=f 2=g~ 3=o
    const int p = 4 * unit + g;                    // permuted xp index
    const bool writer = valid && (g == 3);
    const float kk2 = (g == 2) ? 2.0f : 1.0f;      // tanh via exp(2x)
    const float bsub = (g == 2) ? 2.0f : 1.0f;     // act = 1 - bsub/(e+1)
    const bool isg1 = (g == 1);
    const float sk = (1.0f / (1270.0f * 127.0f)) * kk2;  // dequant*kk2 folded

    // ---- init
    if (tid < 128) { h_lds[0][tid] = 0; h_lds[1][tid] = 0; }
    float c = 0.0f;
    const float* xq_ptr = xp + p;
    float xqv[4];                                  // pre-scaled by kk2
#pragma unroll
    for (int pp = 0; pp < 4; ++pp) xqv[pp] = xq_ptr[pp * GATES] * kk2;
    xq_ptr += 4 * GATES;
    unsigned short* hp = hs + unit;
    __syncthreads();

    for (int t = 0; t < TSEQ; t += 4) {
#pragma unroll
        for (int u = 0; u < 4; ++u) {
            const int cur = u & 1;                 // parity of tt == parity of u

            // ---- A fragments: h_q broadcast, 2 x 16B same-address reads
            i32x4 afr[2];
#pragma unroll
            for (int ch = 0; ch < 2; ++ch) {
                const uint4 q = *(const uint4*)&h_lds[cur][ch * 64 + kg * 16];
                afr[ch] = __builtin_bit_cast(i32x4, q);
            }

            // ---- 2-chunk chained i8 MFMA per tile-slot (R10 form)
            i32x4 acc_s[4];
#pragma unroll
            for (int i = 0; i < 4; ++i) {
                if (i < 3 || w == 7) {
                    i32x4 acc = {0, 0, 0, 0};
                    acc = __builtin_amdgcn_mfma_i32_16x16x64_i8(afr[0], wfrag[i][0], acc, 0, 0, 0);
                    acc = __builtin_amdgcn_mfma_i32_16x16x64_i8(afr[1], wfrag[i][1], acc, 0, 0, 0);
                    acc_s[i] = acc;
                } else {
                    acc_s[i] = (i32x4){0, 0, 0, 0};
                }
            }

            // ---- scalar tile select by kg (3 cndmask on i32)
            int ipre = acc_s[0][0];
            ipre = (kg == 1) ? acc_s[1][0] : ipre;
            ipre = (kg == 2) ? acc_s[2][0] : ipre;
            ipre = (kg == 3) ? acc_s[3][0] : ipre;

            // ---- unified activation (kk2 pre-folded into sk and xqv):
            // act = 1 - bsub * rcp(exp(pre*kk2) + 1)
            const float e = __expf(fmaf((float)ipre, sk, xqv[u]));
            const float act = fmaf(-bsub, rcp_fast(e + 1.0f), 1.0f);

            // ---- quad combine via DPP; both DPPs depend only on act (parallel)
            const float di = qb<0x00>(act);              // act of g0 (i)
            const float dg = qb<0xAA>(act);              // act of g2 (g~)
            const float prod = di * dg;                  // i * g~
            const float cnew = fmaf(act, c, prod);       // g1: f*c + i*g~
            c = isg1 ? cnew : c;                         // c lives on g1
            const float e2 = __expf(c + c);              // tanh(c) on g1
            const float tc = fmaf(-2.0f, rcp_fast(e2 + 1.0f), 1.0f);
            const float hv = act * qb<0x55>(tc);         // g3: o * tanh(c)

            if (writer) {
                const int hq = (int)rintf(hv * 127.0f);
                h_lds[1 - cur][unit] = (char)hq;         // publish int8
                union { __fp16 h; unsigned short u16; } cv;
                cv.h = (__fp16)hv;
                hp[u * HIDDEN] = cv.u16;                 // fire-and-forget f16
            }
            // depth-4 prefetch, pre-scaled (tail overruns into hs region:
            // valid memory, value never consumed)
            xqv[u] = xq_ptr[u * GATES] * kk2;

            LDS_BARRIER();   // new h visible to all waves for next step
        }
        xq_ptr += 4 * GATES;
        hp += 4 * HIDDEN;
    }
}

// ---------------------------------------------------------------------------
// Kernel 3: out[t] = sigmoid(dot(hs_f16[t], W_lin) + b_lin)
// ---------------------------------------------------------------------------
__global__ __launch_bounds__(256) void pred_kernel(
    const unsigned short* __restrict__ hs,   // [TSEQ][100] f16
    const float* __restrict__ wlin,          // [100]
    const float* __restrict__ blin,          // [1]
    float* __restrict__ out)                 // [TSEQ]
{
    __shared__ __align__(16) float wl[HIDDEN];
    const int tid = threadIdx.x;
    if (tid < HIDDEN) wl[tid] = wlin[tid];
    __syncthreads();

    const int t = blockIdx.x * 256 + tid;
    const unsigned short* hrow = hs + (size_t)t * HIDDEN;   // 8B-aligned
    float acc = blin[0];
#pragma unroll
    for (int kk = 0; kk < 25; ++kk) {                       // 25 x uint2 = 100 f16
        const uint2 v = *(const uint2*)&hrow[kk * 4];
        const __fp16 h0 = __builtin_bit_cast(__fp16, (unsigned short)(v.x & 0xffffu));
        const __fp16 h1 = __builtin_bit_cast(__fp16, (unsigned short)(v.x >> 16));
        const __fp16 h2 = __builtin_bit_cast(__fp16, (unsigned short)(v.y & 0xffffu));
        const __fp16 h3 = __builtin_bit_cast(__fp16, (unsigned short)(v.y >> 16));
        acc = fmaf((float)h0, wl[kk * 4 + 0], acc);
        acc = fmaf((float)h1, wl[kk * 4 + 1], acc);
        acc = fmaf((float)h2, wl[kk * 4 + 2], acc);
        acc = fmaf((float)h3, wl[kk * 4 + 3], acc);
    }
    out[t] = sigm(acc);
}

// ---------------------------------------------------------------------------
extern "C" void kernel_launch(void* const* d_in, const int* in_sizes, int n_in,
                              void* d_out, int out_size, void* d_ws, size_t ws_size,
                              hipStream_t stream) {
    const float* x     = (const float*)d_in[0];  // [65536,128]
    const float* W_ih  = (const float*)d_in[1];  // [400,128]
    const float* W_hh  = (const float*)d_in[2];  // [400,100]
    const float* b_ih  = (const float*)d_in[3];  // [400]
    const float* b_hh  = (const float*)d_in[4];  // [400]
    const float* W_lin = (const float*)d_in[5];  // [1,100]
    const float* b_lin = (const float*)d_in[6];  // [1]
    float* out = (float*)d_out;                  // [65536]

    float* xp = (float*)d_ws;                                  // [TSEQ*400] fp32
    unsigned short* hs = (unsigned short*)(xp + (size_t)TSEQ * GATES);  // [TSEQ*100] f16

    xproj_kernel<<<TSEQ / 16, 256, 0, stream>>>(x, W_ih, b_ih, b_hh, xp);
    lstm_rec_kernel<<<1, 512, 0, stream>>>(xp, W_hh, hs);
    pred_kernel<<<TSEQ / 256, 256, 0, stream>>>(hs, W_lin, b_lin, out);
}

// Round 13
// 19286.887 us; speedup vs baseline: 1.1781x; 1.1070x over previous
//
#include <hip/hip_runtime.h>
#include <hip/hip_bf16.h>

#define TSEQ 65536
#define INPUT_SIZE 128
#define HIDDEN 100
#define GATES 400   // 4*HIDDEN

typedef int  __attribute__((ext_vector_type(4))) i32x4;

__device__ __forceinline__ float rcp_fast(float x) { return __builtin_amdgcn_rcpf(x); }
__device__ __forceinline__ float sigm(float x) { return rcp_fast(1.0f + __expf(-x)); }

// DPP quad_perm broadcast within groups of 4 lanes (pure VALU, no LDS).
template <int CTRL>
__device__ __forceinline__ float qb(float v) {
    int i = __builtin_bit_cast(int, v);
    int r = __builtin_amdgcn_mov_dpp(i, CTRL, 0xF, 0xF, true);
    return __builtin_bit_cast(float, r);
}

// barrier without vmcnt drain: LDS-drain + s_barrier + compiler memory fence
#define LDS_BARRIER()                                              \
    do {                                                           \
        asm volatile("s_waitcnt lgkmcnt(0)" ::: "memory");         \
        __builtin_amdgcn_s_barrier();                              \
        asm volatile("" ::: "memory");                             \
    } while (0)

// ---------------------------------------------------------------------------
// Kernel 1: xp_perm[t][4*u + g] = b_ih[j] + b_hh[j] + sum_k x[t][k]*W_ih[j][k]
// where j = g*100 + u (orig gate row). Unit-major/gate-minor layout.
// ---------------------------------------------------------------------------
__global__ __launch_bounds__(256) void xproj_kernel(
    const float* __restrict__ x,     // [TSEQ][128]
    const float* __restrict__ W,     // [400][128]
    const float* __restrict__ bi,    // [400]
    const float* __restrict__ bh,    // [400]
    float* __restrict__ xp)          // [TSEQ][400] (permuted)
{
    __shared__ __align__(16) float xs[16 * 128];
    const int tid = threadIdx.x;
    const int t0 = blockIdx.x * 16;

#pragma unroll
    for (int i = 0; i < 8; ++i)
        xs[i * 256 + tid] = x[(size_t)t0 * 128 + i * 256 + tid];
    __syncthreads();

    const int j1 = tid;
    const int j2 = tid + 256;
    const bool has2 = (j2 < GATES);
    const int p1 = 4 * (j1 % 100) + (j1 / 100);
    const int p2 = has2 ? (4 * (j2 % 100) + (j2 / 100)) : 0;

    float acc1[16], acc2[16];
    const float bias1 = bi[j1] + bh[j1];
    const float bias2 = has2 ? (bi[j2] + bh[j2]) : 0.0f;
#pragma unroll
    for (int tt = 0; tt < 16; ++tt) { acc1[tt] = bias1; acc2[tt] = bias2; }

    const float4* W4 = reinterpret_cast<const float4*>(W);
    const float4* xs4 = reinterpret_cast<const float4*>(xs);

    for (int kk = 0; kk < 32; ++kk) {
        const float4 wa = W4[(size_t)j1 * 32 + kk];
        float4 wb = make_float4(0.f, 0.f, 0.f, 0.f);
        if (has2) wb = W4[(size_t)j2 * 32 + kk];
#pragma unroll
        for (int tt = 0; tt < 16; ++tt) {
            const float4 xv = xs4[tt * 32 + kk];
            acc1[tt] = fmaf(wa.x, xv.x, acc1[tt]);
            acc1[tt] = fmaf(wa.y, xv.y, acc1[tt]);
            acc1[tt] = fmaf(wa.z, xv.z, acc1[tt]);
            acc1[tt] = fmaf(wa.w, xv.w, acc1[tt]);
            acc2[tt] = fmaf(wb.x, xv.x, acc2[tt]);
            acc2[tt] = fmaf(wb.y, xv.y, acc2[tt]);
            acc2[tt] = fmaf(wb.z, xv.z, acc2[tt]);
            acc2[tt] = fmaf(wb.w, xv.w, acc2[tt]);
        }
    }

#pragma unroll
    for (int tt = 0; tt < 16; ++tt) {
        xp[(size_t)(t0 + tt) * GATES + p1] = acc1[tt];
        if (has2) xp[(size_t)(t0 + tt) * GATES + p2] = acc2[tt];
    }
}

// ---------------------------------------------------------------------------
// Kernel 2: LSTM recurrence via INT8 MFMA (v_mfma_i32_16x16x64_i8).
// One block, 512 threads (8 waves), 1 barrier/step.
// Quantization: W_q = rint(W_hh * 1270) (|W|<0.1 by init), h_q = rint(h*127)
// (|h|<1 always). preact = i32_dot * (1/(1270*127)) + xp. i32 accum is exact;
// abs errors comparable to the bf16 path that measured absmax 0.0039.
// TRANSPOSED: A = h_q replicated over 16 rows (one b128 broadcast per K-chunk,
// 2 chunks for K=128-padded-100), B = W_q tile (col j of tile ti = orig gate
// row (j&3)*100 + 4ti + (j>>2)). D rows replicated => lane (bq=l>>4, c=l&15)
// selects tile-slot bq's col-c i32 preact with 3 cndmask. Gates of a unit are
// a lane-quad -> DPP combine. h published as ONE ds_write_b8.
// EXACT R10 SOURCE (19.1 ms measured): R11/R12 "improvements" both regressed
// via codegen schedule sensitivity -- do not perturb this loop body.
// ---------------------------------------------------------------------------
__global__ __launch_bounds__(512, 1) void lstm_rec_kernel(
    const float* __restrict__ xp,    // [TSEQ][400] permuted, includes biases
    const float* __restrict__ Whh,   // [400][100] original layout
    unsigned short* __restrict__ hs) // [TSEQ][100] f16
{
    __shared__ __align__(16) char h_lds[2][128];   // int8 h, zero-padded to 128

    const int tid = threadIdx.x;
    const int lane = tid & 63;
    const int w = tid >> 6;          // wave 0..7
    const int kg = lane >> 4;        // k-group for frags; tile-slot for cell
    const int cc = lane & 15;        // B col within tile = gate slot

    // ---- W_q fragments (B operand): 4 tile-slots x 2 K-chunks, 4 dwords each
    // wave w: tiles 3w..3w+2 ; slot 3 = tile 24 (wave 7 only)
    i32x4 wfrag[4][2];
#pragma unroll
    for (int i = 0; i < 4; ++i) {
        const int ti = (i < 3) ? (3 * w + i) : 24;
        const bool valid = (i < 3) || (w == 7);
        const int orow = (cc & 3) * 100 + 4 * ti + (cc >> 2);  // orig W_hh row
#pragma unroll
        for (int ch = 0; ch < 2; ++ch) {
            const int k0 = 64 * ch + 16 * kg;
            int dw[4];
#pragma unroll
            for (int d = 0; d < 4; ++d) {
                unsigned pk = 0;
#pragma unroll
                for (int b = 0; b < 4; ++b) {
                    const int k = k0 + 4 * d + b;
                    float wv = (valid && k < 100) ? Whh[(size_t)orow * 100 + k] : 0.0f;
                    int q = (int)rintf(wv * 1270.0f);
                    q = (q > 127) ? 127 : ((q < -127) ? -127 : q);
                    pk |= ((unsigned)(q & 0xff)) << (8 * b);
                }
                dw[d] = (int)pk;
            }
            wfrag[i][ch] = i32x4{dw[0], dw[1], dw[2], dw[3]};
        }
    }

    // ---- lane roles (loop-invariant)
    const bool valid = (kg < 3) || (w == 7);
    const int mytile = (kg < 3) ? (3 * w + kg) : 24;
    const int unit = 4 * mytile + (cc >> 2);
    const int g = cc & 3;                          // 0=i 1=f 2=g~ 3=o
    const int p = 4 * unit + g;                    // permuted xp index
    const bool writer = valid && (g == 3);
    const float kk2 = (g == 2) ? 2.0f : 1.0f;      // tanh via exp(2x)
    const float bsub = (g == 2) ? 2.0f : 1.0f;     // act = 1 - bsub/(e+1)
    const bool isg1 = (g == 1);
    const float SCALE = 1.0f / (1270.0f * 127.0f); // dequant factor

    // ---- init
    if (tid < 128) { h_lds[0][tid] = 0; h_lds[1][tid] = 0; }
    float c = 0.0f;
    const float* xq_ptr = xp + p;
    float xqv[4];
#pragma unroll
    for (int pp = 0; pp < 4; ++pp) xqv[pp] = xq_ptr[pp * GATES];
    xq_ptr += 4 * GATES;
    unsigned short* hp = hs + unit;
    __syncthreads();

    for (int t = 0; t < TSEQ; t += 4) {
#pragma unroll
        for (int u = 0; u < 4; ++u) {
            const int cur = u & 1;                 // parity of tt == parity of u

            // ---- A fragments: h_q broadcast, 2 x 16B same-address reads
            i32x4 afr[2];
#pragma unroll
            for (int ch = 0; ch < 2; ++ch) {
                const uint4 q = *(const uint4*)&h_lds[cur][ch * 64 + kg * 16];
                afr[ch] = __builtin_bit_cast(i32x4, q);
            }

            // ---- 2-chunk chained i8 MFMA per tile-slot
            i32x4 acc_s[4];
#pragma unroll
            for (int i = 0; i < 4; ++i) {
                if (i < 3 || w == 7) {
                    i32x4 acc = {0, 0, 0, 0};
                    acc = __builtin_amdgcn_mfma_i32_16x16x64_i8(afr[0], wfrag[i][0], acc, 0, 0, 0);
                    acc = __builtin_amdgcn_mfma_i32_16x16x64_i8(afr[1], wfrag[i][1], acc, 0, 0, 0);
                    acc_s[i] = acc;
                } else {
                    acc_s[i] = (i32x4){0, 0, 0, 0};
                }
            }

            // ---- scalar tile select by kg (3 cndmask on i32)
            int ipre = acc_s[0][0];
            ipre = (kg == 1) ? acc_s[1][0] : ipre;
            ipre = (kg == 2) ? acc_s[2][0] : ipre;
            ipre = (kg == 3) ? acc_s[3][0] : ipre;
            const float pre = fmaf((float)ipre, SCALE, xqv[u]);

            // ---- unified activation: act = 1 - bsub * rcp(exp(kk2*pre)+1)
            const float e = __expf(pre * kk2);
            const float act = fmaf(-bsub, rcp_fast(e + 1.0f), 1.0f);

            // ---- quad combine via DPP (lanes g0=i g1=f g2=g~ g3=o)
            const float prod = act * qb<0xAA>(act);          // g0: i * g~
            const float cnew = fmaf(act, c, qb<0x00>(prod)); // g1: f*c + i*g~
            c = isg1 ? cnew : c;                             // c lives on g1
            const float e2 = __expf(c + c);                  // tanh(c) on g1
            const float tc = fmaf(-2.0f, rcp_fast(e2 + 1.0f), 1.0f);
            const float hv = act * qb<0x55>(tc);             // g3: o * tanh(c)

            if (writer) {
                const int hq = (int)rintf(hv * 127.0f);
                h_lds[1 - cur][unit] = (char)hq;             // publish int8
                union { __fp16 h; unsigned short u16; } cv;
                cv.h = (__fp16)hv;
                hp[u * HIDDEN] = cv.u16;                     // fire-and-forget f16
            }
            // depth-4 prefetch (tail overruns into hs region: valid memory,
            // value never consumed)
            xqv[u] = xq_ptr[u * GATES];

            LDS_BARRIER();   // new h visible to all waves for next step
        }
        xq_ptr += 4 * GATES;
        hp += 4 * HIDDEN;
    }
}

// ---------------------------------------------------------------------------
// Kernel 3: out[t] = sigmoid(dot(hs_f16[t], W_lin) + b_lin)
// ---------------------------------------------------------------------------
__global__ __launch_bounds__(256) void pred_kernel(
    const unsigned short* __restrict__ hs,   // [TSEQ][100] f16
    const float* __restrict__ wlin,          // [100]
    const float* __restrict__ blin,          // [1]
    float* __restrict__ out)                 // [TSEQ]
{
    __shared__ __align__(16) float wl[HIDDEN];
    const int tid = threadIdx.x;
    if (tid < HIDDEN) wl[tid] = wlin[tid];
    __syncthreads();

    const int t = blockIdx.x * 256 + tid;
    const unsigned short* hrow = hs + (size_t)t * HIDDEN;   // 8B-aligned
    float acc = blin[0];
#pragma unroll
    for (int kk = 0; kk < 25; ++kk) {                       // 25 x uint2 = 100 f16
        const uint2 v = *(const uint2*)&hrow[kk * 4];
        const __fp16 h0 = __builtin_bit_cast(__fp16, (unsigned short)(v.x & 0xffffu));
        const __fp16 h1 = __builtin_bit_cast(__fp16, (unsigned short)(v.x >> 16));
        const __fp16 h2 = __builtin_bit_cast(__fp16, (unsigned short)(v.y & 0xffffu));
        const __fp16 h3 = __builtin_bit_cast(__fp16, (unsigned short)(v.y >> 16));
        acc = fmaf((float)h0, wl[kk * 4 + 0], acc);
        acc = fmaf((float)h1, wl[kk * 4 + 1], acc);
        acc = fmaf((float)h2, wl[kk * 4 + 2], acc);
        acc = fmaf((float)h3, wl[kk * 4 + 3], acc);
    }
    out[t] = sigm(acc);
}

// ---------------------------------------------------------------------------
extern "C" void kernel_launch(void* const* d_in, const int* in_sizes, int n_in,
                              void* d_out, int out_size, void* d_ws, size_t ws_size,
                              hipStream_t stream) {
    const float* x     = (const float*)d_in[0];  // [65536,128]
    const float* W_ih  = (const float*)d_in[1];  // [400,128]
    const float* W_hh  = (const float*)d_in[2];  // [400,100]
    const float* b_ih  = (const float*)d_in[3];  // [400]
    const float* b_hh  = (const float*)d_in[4];  // [400]
    const float* W_lin = (const float*)d_in[5];  // [1,100]
    const float* b_lin = (const float*)d_in[6];  // [1]
    float* out = (float*)d_out;                  // [65536]

    float* xp = (float*)d_ws;                                  // [TSEQ*400] fp32
    unsigned short* hs = (unsigned short*)(xp + (size_t)TSEQ * GATES);  // [TSEQ*100] f16

    xproj_kernel<<<TSEQ / 16, 256, 0, stream>>>(x, W_ih, b_ih, b_hh, xp);
    lstm_rec_kernel<<<1, 512, 0, stream>>>(xp, W_hh, hs);
    pred_kernel<<<TSEQ / 256, 256, 0, stream>>>(hs, W_lin, b_lin, out);
}